// Round 3
// baseline (360.925 us; speedup 1.0000x reference)
//
#include <hip/hip_runtime.h>
#include <hip/hip_fp16.h>
#include <cstdint>
#include <cstddef>

// OccupancyModel: feats = grid[round(clip(p*127))]  (2M x 16 gather)
//   h1 = relu(feats @ W1^T + b1); h2 = relu(h1 @ W2^T + b2); occ = tanh(h2 @ W3^T + b3)
//
// R9: fix R7/R8's pipeline-order bug. R8 failed absmax 0.41: the loop did
//   loadFeat(u&1, tile u+2)   // OVERWRITES slot u&1
//   ... read Fa[u&1]          // expected tile u -> got tile u+2
// i.e. the refill clobbered the slot before consumption (program order is
// authoritative; "the compiler will SSA-rename" was wrong). Fix: build
// bfrag (f32->f16 converts copy the values out) BEFORE issuing the refill.
// The prefetch still has the whole MFMA+shuffle+L2+L3 phase to cover the
// gather latency.
//
// R7 rationale (vs R6's LDS-DMA): rocprof showed latency profile (HBM 19%,
// Mfma 10%, VALU 40%, occ 28%) + 9.3M LDS bank-conflict cycles from the
// stride-64B ds_read_b128, and the per-chunk vmcnt(0) drain serialized
// DMA vs compute. The B-fragment ownership maps 1:1 onto the 64B grid
// cell: lane (quad<2, l15) needs feats quad*8..+7 of point l15 = two
// float4s at cell+quad*32 -> gather straight to VGPRs; no LDS at all.
//
// MLP core verified R1-R6 (absmax 1.95e-3): fp16 MFMA 16x16x32,
// H^T = W @ feats^T, points on n-dim (col=lane&15); b1 folded into the
// layer-1 K-pad slot; layer1->2 relayout via 16 cross-quad shuffles;
// tanh = 1 - 2/(exp(2x)+1).

typedef _Float16 half8 __attribute__((ext_vector_type(8)));
typedef float float4v __attribute__((ext_vector_type(4)));

#define WPB 4   // waves per block
#define NT  16  // tiles per wave (256 points)

__device__ inline uint32_t pack_f16x2(float a, float b) {
    union { _Float16 h[2]; uint32_t u; } v;
    v.h[0] = (_Float16)a;
    v.h[1] = (_Float16)b;
    return v.u;
}

__global__ __launch_bounds__(256, 4) void occ_mlp_kernel(
    const float* __restrict__ pts,
    const float* __restrict__ grid,
    const float* __restrict__ W1, const float* __restrict__ b1,
    const float* __restrict__ W2, const float* __restrict__ b2,
    const float* __restrict__ W3, const float* __restrict__ b3,
    float* __restrict__ out, int nPoints)
{
    const int lane = threadIdx.x & 63;
    const int l15  = lane & 15;
    const int quad = lane >> 4;
    const int wib  = threadIdx.x >> 6;
    const int tile0 = (blockIdx.x * WPB + wib) * NT;
    const int nTiles = (nPoints + 15) >> 4;
    if (tile0 >= nTiles) return;
    const int maxP = nPoints - 1;

    // ---- loop-invariant weight fragments ----
    // A layout: A[m = lane&15][k = quad*8 + j]. Layer1 K=16 padded to 32;
    // b1 folded at k=16 (quad2 j=0), bfrag's k=16 slot = 1.0.
    half8 A1[4];
#pragma unroll
    for (int t = 0; t < 4; ++t) {
        half8 f = {};
        if (quad < 2) {
            const float* row = W1 + (16 * t + l15) * 16 + quad * 8;
#pragma unroll
            for (int j = 0; j < 8; ++j) f[j] = (_Float16)row[j];
        } else if (quad == 2) {
            f[0] = (_Float16)b1[16 * t + l15];
        }
        A1[t] = f;
    }
    half8 A2[4][2];
#pragma unroll
    for (int t = 0; t < 4; ++t)
#pragma unroll
        for (int kk = 0; kk < 2; ++kk) {
            const float* row = W2 + (16 * t + l15) * 64 + 32 * kk + 8 * quad;
            half8 f;
#pragma unroll
            for (int j = 0; j < 8; ++j) f[j] = (_Float16)row[j];
            A2[t][kk] = f;
        }
    // C/D layout: col = lane&15 (point), row = quad*4 + reg.
    float4v bias2[4];
    float w3v[4][4];
#pragma unroll
    for (int t = 0; t < 4; ++t)
#pragma unroll
        for (int r = 0; r < 4; ++r) {
            int h = 16 * t + 4 * quad + r;
            bias2[t][r] = b2[h];
            w3v[t][r]   = W3[h];
        }
    const float bias3 = b3[0];

    // layer1->layer2 cross-quad shuffle plan
    const int src0 = l15 + 16 * ((2 * quad) & 3);
    const int src1 = l15 + 16 * ((2 * quad + 1) & 3);
    const bool sel = (quad >> 1) != 0;

    // ---- register pipeline state ----
    // pts ring: 4 tiles deep (each lane holds point l15's coords, 4-way
    // redundant across quads -> same-line broadcast in L1).
    float Px[4], Py[4], Pz[4];
    // feature prefetch: 2 tiles deep; lane (quad<2, l15) owns feats
    // quad*8..quad*8+7 of point l15 (= its layer-1 B fragment, pre-cvt).
    float4 Fa[2], Fb[2];

    auto loadPts = [&](int slot, int u) {
        int p = (tile0 + u) * 16 + l15;
        p = p > maxP ? maxP : p;
        const float* q = pts + 3 * p;
        Px[slot] = q[0]; Py[slot] = q[1]; Pz[slot] = q[2];
    };
    auto loadFeat = [&](int fslot, int pslot) {
        if (quad < 2) {
            const int ix = (int)rintf(fminf(fmaxf(Px[pslot] * 127.0f, 0.0f), 127.0f));
            const int iy = (int)rintf(fminf(fmaxf(Py[pslot] * 127.0f, 0.0f), 127.0f));
            const int iz = (int)rintf(fminf(fmaxf(Pz[pslot] * 127.0f, 0.0f), 127.0f));
            const int ofs = ((((ix << 7) | iy) << 7) | iz) << 4;  // floats
            const float4* g = reinterpret_cast<const float4*>(grid + ofs + (quad << 3));
            Fa[fslot] = g[0];
            Fb[fslot] = g[1];
        }
    };

    // ---- prologue: fill rings ----
    loadPts(0, 0); loadPts(1, 1); loadPts(2, 2); loadPts(3, 3);
    loadFeat(0, 0);   // tile 0
    loadFeat(1, 1);   // tile 1

    float o[4];

#pragma unroll
    for (int u = 0; u < NT; ++u) {
        // ---- CONSUME slot u&1 first (tile u's features -> bfrag) ----
        // The f32->f16 converts copy the values out of Fa/Fb; only after
        // this may the slot be refilled (R8's bug: refill-before-consume).
        half8 bfrag = {};
        if (quad < 2) {
            const float4 f0 = Fa[u & 1];
            const float4 f1 = Fb[u & 1];
            bfrag[0] = (_Float16)f0.x; bfrag[1] = (_Float16)f0.y;
            bfrag[2] = (_Float16)f0.z; bfrag[3] = (_Float16)f0.w;
            bfrag[4] = (_Float16)f1.x; bfrag[5] = (_Float16)f1.y;
            bfrag[6] = (_Float16)f1.z; bfrag[7] = (_Float16)f1.w;
        } else if (quad == 2) {
            bfrag[0] = (_Float16)1.0f;  // multiplies the folded b1 column
        }

        // ---- refill pipeline: these fly across this tile's compute ----
        if (u + 4 < NT) loadPts(u & 3, u + 4);          // slot u&3 free (read 2 iters ago)
        if (u + 2 < NT) loadFeat(u & 1, (u + 2) & 3);   // slot u&1 consumed above

        // layer 1 (bias via folded K-slot)
        float4v C1[4];
#pragma unroll
        for (int t = 0; t < 4; ++t) {
            float4v zacc = {};
            C1[t] = __builtin_amdgcn_mfma_f32_16x16x32_f16(A1[t], bfrag, zacc, 0, 0, 0);
        }

        // relu + fp16 pack
        uint32_t P[4][2];
#pragma unroll
        for (int t = 0; t < 4; ++t) {
            P[t][0] = pack_f16x2(fmaxf(C1[t][0], 0.0f), fmaxf(C1[t][1], 0.0f));
            P[t][1] = pack_f16x2(fmaxf(C1[t][2], 0.0f), fmaxf(C1[t][3], 0.0f));
        }

        // cross-quad shuffle into layer-2 B fragments
        union Frag { uint32_t u[4]; half8 h; } B2[2];
#pragma unroll
        for (int kk = 0; kk < 2; ++kk) {
            const uint32_t x0a = (uint32_t)__shfl((int)P[2 * kk    ][0], src0);
            const uint32_t x0b = (uint32_t)__shfl((int)P[2 * kk + 1][0], src0);
            const uint32_t x1a = (uint32_t)__shfl((int)P[2 * kk    ][1], src0);
            const uint32_t x1b = (uint32_t)__shfl((int)P[2 * kk + 1][1], src0);
            const uint32_t y0a = (uint32_t)__shfl((int)P[2 * kk    ][0], src1);
            const uint32_t y0b = (uint32_t)__shfl((int)P[2 * kk + 1][0], src1);
            const uint32_t y1a = (uint32_t)__shfl((int)P[2 * kk    ][1], src1);
            const uint32_t y1b = (uint32_t)__shfl((int)P[2 * kk + 1][1], src1);
            B2[kk].u[0] = sel ? x0b : x0a;
            B2[kk].u[1] = sel ? x1b : x1a;
            B2[kk].u[2] = sel ? y0b : y0a;
            B2[kk].u[3] = sel ? y1b : y1a;
        }

        // layer 2 (bias as initial accumulator)
        float4v C2[4];
#pragma unroll
        for (int t = 0; t < 4; ++t) C2[t] = bias2[t];
#pragma unroll
        for (int kk = 0; kk < 2; ++kk)
#pragma unroll
            for (int t = 0; t < 4; ++t)
                C2[t] = __builtin_amdgcn_mfma_f32_16x16x32_f16(A2[t][kk], B2[kk].h, C2[t], 0, 0, 0);

        // layer 3: dot(relu(h2), w3), reduce across quads (broadcasts)
        float z = 0.0f;
#pragma unroll
        for (int t = 0; t < 4; ++t)
#pragma unroll
            for (int r = 0; r < 4; ++r)
                z = fmaf(fmaxf(C2[t][r], 0.0f), w3v[t][r], z);
        z += __shfl_xor(z, 16);
        z += __shfl_xor(z, 32);
        const float e = __expf(2.0f * (z + bias3));
        o[u & 3] = fmaf(-2.0f, __builtin_amdgcn_rcpf(e + 1.0f), 1.0f);

        // every 4 tiles: one coalesced 256B store (64 points)
        if ((u & 3) == 3) {
            const float osel = (quad == 0) ? o[0] : (quad == 1) ? o[1]
                             : (quad == 2) ? o[2] : o[3];
            const int pstore = (tile0 + (u & ~3)) * 16 + lane;
            if (pstore <= maxP) out[pstore] = osel;
        }

        // pin the load schedule to the written pipeline depth: memory ops
        // cannot cross this fence; VALU/MFMA still schedule freely.
        asm volatile("" ::: "memory");
    }
}

extern "C" void kernel_launch(void* const* d_in, const int* in_sizes, int n_in,
                              void* d_out, int out_size, void* d_ws, size_t ws_size,
                              hipStream_t stream)
{
    const float* pts  = (const float*)d_in[0];
    const float* grid = (const float*)d_in[1];
    const float* W1   = (const float*)d_in[2];
    const float* b1   = (const float*)d_in[3];
    const float* W2   = (const float*)d_in[4];
    const float* b2   = (const float*)d_in[5];
    const float* W3   = (const float*)d_in[6];
    const float* b3   = (const float*)d_in[7];
    float* out = (float*)d_out;
    const int nPoints = in_sizes[0] / 3;

    const int nTiles = (nPoints + 15) >> 4;
    const int tilesPerBlock = WPB * NT;              // 64
    const int nBlocks = (nTiles + tilesPerBlock - 1) / tilesPerBlock;  // 2048

    occ_mlp_kernel<<<dim3(nBlocks), dim3(256), 0, stream>>>(
        pts, grid, W1, b1, W2, b2, W3, b3, out, nPoints);
}

// Round 4
// 272.694 us; speedup vs baseline: 1.3236x; 1.3236x over previous
//
#include <hip/hip_runtime.h>
#include <hip/hip_fp16.h>
#include <cstdint>
#include <cstddef>

// OccupancyModel: feats = grid[round(clip(p*127))]  (2M x 16 gather)
//   h1 = relu(feats @ W1^T + b1); h2 = relu(h1 @ W2^T + b2); occ = tanh(h2 @ W3^T + b3)
//
// R10: R9 was correct (absmax 1.95e-3) but 2x slower than R6 (205 vs 100us).
// Counters: WRITE_SIZE 8MB -> 190MB (output is 8MB => SCRATCH SPILL),
// FETCH +39MB (spill fills), VGPR_Count 64 << ~130 live state. Under
// __launch_bounds__(256,4) (cap 512/4=128) the allocator picked a
// 64-reg/high-occupancy point and spilled the pipeline+weights to scratch.
// Fix: launch_bounds(256,3) (cap 170, same as proven R6) + pts ring 4->3
// deep. ~130 live regs now fit; 12 waves/CU is ample TLP for the depth-2
// feature prefetch.
//
// R9: consume-before-refill order (R8's bug: refill clobbered the slot
// before the f32->f16 converts copied it out).
//
// R7 rationale (vs R6's LDS-DMA): B-fragment ownership maps 1:1 onto the
// 64B grid cell: lane (quad<2, l15) needs feats quad*8..+7 of point l15 =
// two float4s at cell+quad*32 -> gather straight to VGPRs; no LDS staging,
// no ds_read conflicts (R6's 9.3M - 4.2M shuffle residue), no vmcnt drains.
//
// MLP core verified R1-R9 (absmax 1.95e-3): fp16 MFMA 16x16x32,
// H^T = W @ feats^T, points on n-dim (col=lane&15); b1 folded into the
// layer-1 K-pad slot; layer1->2 relayout via 16 cross-quad shuffles;
// tanh = 1 - 2/(exp(2x)+1).

typedef _Float16 half8 __attribute__((ext_vector_type(8)));
typedef float float4v __attribute__((ext_vector_type(4)));

#define WPB 4   // waves per block
#define NT  16  // tiles per wave (256 points)

__device__ inline uint32_t pack_f16x2(float a, float b) {
    union { _Float16 h[2]; uint32_t u; } v;
    v.h[0] = (_Float16)a;
    v.h[1] = (_Float16)b;
    return v.u;
}

__global__ __launch_bounds__(256, 3) void occ_mlp_kernel(
    const float* __restrict__ pts,
    const float* __restrict__ grid,
    const float* __restrict__ W1, const float* __restrict__ b1,
    const float* __restrict__ W2, const float* __restrict__ b2,
    const float* __restrict__ W3, const float* __restrict__ b3,
    float* __restrict__ out, int nPoints)
{
    const int lane = threadIdx.x & 63;
    const int l15  = lane & 15;
    const int quad = lane >> 4;
    const int wib  = threadIdx.x >> 6;
    const int tile0 = (blockIdx.x * WPB + wib) * NT;
    const int nTiles = (nPoints + 15) >> 4;
    if (tile0 >= nTiles) return;
    const int maxP = nPoints - 1;

    // ---- loop-invariant weight fragments ----
    // A layout: A[m = lane&15][k = quad*8 + j]. Layer1 K=16 padded to 32;
    // b1 folded at k=16 (quad2 j=0), bfrag's k=16 slot = 1.0.
    half8 A1[4];
#pragma unroll
    for (int t = 0; t < 4; ++t) {
        half8 f = {};
        if (quad < 2) {
            const float* row = W1 + (16 * t + l15) * 16 + quad * 8;
#pragma unroll
            for (int j = 0; j < 8; ++j) f[j] = (_Float16)row[j];
        } else if (quad == 2) {
            f[0] = (_Float16)b1[16 * t + l15];
        }
        A1[t] = f;
    }
    half8 A2[4][2];
#pragma unroll
    for (int t = 0; t < 4; ++t)
#pragma unroll
        for (int kk = 0; kk < 2; ++kk) {
            const float* row = W2 + (16 * t + l15) * 64 + 32 * kk + 8 * quad;
            half8 f;
#pragma unroll
            for (int j = 0; j < 8; ++j) f[j] = (_Float16)row[j];
            A2[t][kk] = f;
        }
    // C/D layout: col = lane&15 (point), row = quad*4 + reg.
    float4v bias2[4];
    float w3v[4][4];
#pragma unroll
    for (int t = 0; t < 4; ++t)
#pragma unroll
        for (int r = 0; r < 4; ++r) {
            int h = 16 * t + 4 * quad + r;
            bias2[t][r] = b2[h];
            w3v[t][r]   = W3[h];
        }
    const float bias3 = b3[0];

    // layer1->layer2 cross-quad shuffle plan
    const int src0 = l15 + 16 * ((2 * quad) & 3);
    const int src1 = l15 + 16 * ((2 * quad + 1) & 3);
    const bool sel = (quad >> 1) != 0;

    // ---- register pipeline state ----
    // pts ring: 3 tiles deep (each lane holds point l15's coords; 4-way
    // redundant across quads -> same-line merge in the coalescer).
    float Px[3], Py[3], Pz[3];
    // feature prefetch: 2 tiles deep; lane (quad<2, l15) owns feats
    // quad*8..quad*8+7 of point l15 (= its layer-1 B fragment, pre-cvt).
    float4 Fa[2], Fb[2];

    auto loadPts = [&](int slot, int u) {
        int p = (tile0 + u) * 16 + l15;
        p = p > maxP ? maxP : p;
        const float* q = pts + 3 * p;
        Px[slot] = q[0]; Py[slot] = q[1]; Pz[slot] = q[2];
    };
    auto loadFeat = [&](int fslot, int pslot) {
        if (quad < 2) {
            const int ix = (int)rintf(fminf(fmaxf(Px[pslot] * 127.0f, 0.0f), 127.0f));
            const int iy = (int)rintf(fminf(fmaxf(Py[pslot] * 127.0f, 0.0f), 127.0f));
            const int iz = (int)rintf(fminf(fmaxf(Pz[pslot] * 127.0f, 0.0f), 127.0f));
            const int ofs = ((((ix << 7) | iy) << 7) | iz) << 4;  // floats
            const float4* g = reinterpret_cast<const float4*>(grid + ofs + (quad << 3));
            Fa[fslot] = g[0];
            Fb[fslot] = g[1];
        }
    };

    // ---- prologue: fill rings ----
    loadPts(0, 0); loadPts(1, 1); loadPts(2, 2);
    loadFeat(0, 0);   // tile 0
    loadFeat(1, 1);   // tile 1

    float o[4];

#pragma unroll
    for (int u = 0; u < NT; ++u) {
        // ---- CONSUME feat slot u&1 first (tile u's features -> bfrag) ----
        // f32->f16 converts copy the values out; only then may the slot be
        // refilled (R8's bug: refill-before-consume).
        half8 bfrag = {};
        if (quad < 2) {
            const float4 f0 = Fa[u & 1];
            const float4 f1 = Fb[u & 1];
            bfrag[0] = (_Float16)f0.x; bfrag[1] = (_Float16)f0.y;
            bfrag[2] = (_Float16)f0.z; bfrag[3] = (_Float16)f0.w;
            bfrag[4] = (_Float16)f1.x; bfrag[5] = (_Float16)f1.y;
            bfrag[6] = (_Float16)f1.z; bfrag[7] = (_Float16)f1.w;
        } else if (quad == 2) {
            bfrag[0] = (_Float16)1.0f;  // multiplies the folded b1 column
        }

        // ---- refill pipeline: these fly across this tile's compute ----
        // feat for tile u+2 uses pts slot (u+2)%3 (written at iter u-1);
        // pts slot u%3 (tile u -> tile u+3) was last read at iter u-2.
        if (u + 2 < NT) loadFeat(u & 1, (u + 2) % 3);
        if (u + 3 < NT) loadPts(u % 3, u + 3);

        // layer 1 (bias via folded K-slot)
        float4v C1[4];
#pragma unroll
        for (int t = 0; t < 4; ++t) {
            float4v zacc = {};
            C1[t] = __builtin_amdgcn_mfma_f32_16x16x32_f16(A1[t], bfrag, zacc, 0, 0, 0);
        }

        // relu + fp16 pack
        uint32_t P[4][2];
#pragma unroll
        for (int t = 0; t < 4; ++t) {
            P[t][0] = pack_f16x2(fmaxf(C1[t][0], 0.0f), fmaxf(C1[t][1], 0.0f));
            P[t][1] = pack_f16x2(fmaxf(C1[t][2], 0.0f), fmaxf(C1[t][3], 0.0f));
        }

        // cross-quad shuffle into layer-2 B fragments
        union Frag { uint32_t u[4]; half8 h; } B2[2];
#pragma unroll
        for (int kk = 0; kk < 2; ++kk) {
            const uint32_t x0a = (uint32_t)__shfl((int)P[2 * kk    ][0], src0);
            const uint32_t x0b = (uint32_t)__shfl((int)P[2 * kk + 1][0], src0);
            const uint32_t x1a = (uint32_t)__shfl((int)P[2 * kk    ][1], src0);
            const uint32_t x1b = (uint32_t)__shfl((int)P[2 * kk + 1][1], src0);
            const uint32_t y0a = (uint32_t)__shfl((int)P[2 * kk    ][0], src1);
            const uint32_t y0b = (uint32_t)__shfl((int)P[2 * kk + 1][0], src1);
            const uint32_t y1a = (uint32_t)__shfl((int)P[2 * kk    ][1], src1);
            const uint32_t y1b = (uint32_t)__shfl((int)P[2 * kk + 1][1], src1);
            B2[kk].u[0] = sel ? x0b : x0a;
            B2[kk].u[1] = sel ? x1b : x1a;
            B2[kk].u[2] = sel ? y0b : y0a;
            B2[kk].u[3] = sel ? y1b : y1a;
        }

        // layer 2 (bias as initial accumulator)
        float4v C2[4];
#pragma unroll
        for (int t = 0; t < 4; ++t) C2[t] = bias2[t];
#pragma unroll
        for (int kk = 0; kk < 2; ++kk)
#pragma unroll
            for (int t = 0; t < 4; ++t)
                C2[t] = __builtin_amdgcn_mfma_f32_16x16x32_f16(A2[t][kk], B2[kk].h, C2[t], 0, 0, 0);

        // layer 3: dot(relu(h2), w3), reduce across quads (broadcasts)
        float z = 0.0f;
#pragma unroll
        for (int t = 0; t < 4; ++t)
#pragma unroll
            for (int r = 0; r < 4; ++r)
                z = fmaf(fmaxf(C2[t][r], 0.0f), w3v[t][r], z);
        z += __shfl_xor(z, 16);
        z += __shfl_xor(z, 32);
        const float e = __expf(2.0f * (z + bias3));
        o[u & 3] = fmaf(-2.0f, __builtin_amdgcn_rcpf(e + 1.0f), 1.0f);

        // every 4 tiles: one coalesced 256B store (64 points)
        if ((u & 3) == 3) {
            const float osel = (quad == 0) ? o[0] : (quad == 1) ? o[1]
                             : (quad == 2) ? o[2] : o[3];
            const int pstore = (tile0 + (u & ~3)) * 16 + lane;
            if (pstore <= maxP) out[pstore] = osel;
        }

        // pin the load schedule to the written pipeline depth: memory ops
        // cannot cross this fence; VALU/MFMA still schedule freely.
        asm volatile("" ::: "memory");
    }
}

extern "C" void kernel_launch(void* const* d_in, const int* in_sizes, int n_in,
                              void* d_out, int out_size, void* d_ws, size_t ws_size,
                              hipStream_t stream)
{
    const float* pts  = (const float*)d_in[0];
    const float* grid = (const float*)d_in[1];
    const float* W1   = (const float*)d_in[2];
    const float* b1   = (const float*)d_in[3];
    const float* W2   = (const float*)d_in[4];
    const float* b2   = (const float*)d_in[5];
    const float* W3   = (const float*)d_in[6];
    const float* b3   = (const float*)d_in[7];
    float* out = (float*)d_out;
    const int nPoints = in_sizes[0] / 3;

    const int nTiles = (nPoints + 15) >> 4;
    const int tilesPerBlock = WPB * NT;              // 64
    const int nBlocks = (nTiles + tilesPerBlock - 1) / tilesPerBlock;  // 2048

    occ_mlp_kernel<<<dim3(nBlocks), dim3(256), 0, stream>>>(
        pts, grid, W1, b1, W2, b2, W3, b3, out, nPoints);
}

// Round 5
// 261.911 us; speedup vs baseline: 1.3780x; 1.0412x over previous
//
#include <hip/hip_runtime.h>
#include <hip/hip_fp16.h>
#include <cstdint>
#include <cstddef>

// OccupancyModel: feats = grid[round(clip(p*127))]  (2M x 16 gather)
//   h1 = relu(feats @ W1^T + b1); h2 = relu(h1 @ W2^T + b2); occ = tanh(h2 @ W3^T + b3)
//
// R11: deepen the register pipeline. R10 (116us) was correct + spill-free
// but starved of memory parallelism: only 2 feature-tiles (4 VMEM instrs)
// in flight per wave -> MfmaUtil 8.7 / VALU 33 / HBM 16%, all waves parked
// on vmcnt at the bfrag consume. R6's LDS-DMA version (100us) won purely by
// keeping 4x more bytes in flight. Fix here: feature prefetch 2->4 tiles
// (Fa/Fb[4]), pts ring 3->6, ~100 VGPR total - under the 128 occupancy
// cliff and the 170 launch_bounds(256,3) cap (R10's anti-spill lesson).
// All ring indices stay compile-time under full unroll; consume-before-
// refill preserved (R9's lesson).
//
// Pipeline schedule (iter u): consume feat slot u&3 (tile u) -> refill
// feat slot u&3 with tile u+4 (pts slot (u+4)%6, written at iter u-2) ->
// load pts tile u+6 into slot u%6 (last read at iter u-4). 2-iter cover
// on pts->feat dependency, 4-iter cover on feat->consume.
//
// R7 rationale (vs R6 LDS): B-fragment ownership maps 1:1 onto the 64B
// grid cell: lane (quad<2, l15) needs feats quad*8..+7 of point l15 = two
// float4s at cell+quad*32 -> gather straight to VGPRs; no LDS staging,
// no ds_read bank conflicts, no vmcnt(0) drains.
//
// MLP core verified R1-R10 (absmax 1.95e-3): fp16 MFMA 16x16x32,
// H^T = W @ feats^T, points on n-dim (col=lane&15); b1 folded into the
// layer-1 K-pad slot; layer1->2 relayout via 16 cross-quad shuffles;
// tanh = 1 - 2/(exp(2x)+1).

typedef _Float16 half8 __attribute__((ext_vector_type(8)));
typedef float float4v __attribute__((ext_vector_type(4)));

#define WPB 4   // waves per block
#define NT  16  // tiles per wave (256 points)

__device__ inline uint32_t pack_f16x2(float a, float b) {
    union { _Float16 h[2]; uint32_t u; } v;
    v.h[0] = (_Float16)a;
    v.h[1] = (_Float16)b;
    return v.u;
}

__global__ __launch_bounds__(256, 3) void occ_mlp_kernel(
    const float* __restrict__ pts,
    const float* __restrict__ grid,
    const float* __restrict__ W1, const float* __restrict__ b1,
    const float* __restrict__ W2, const float* __restrict__ b2,
    const float* __restrict__ W3, const float* __restrict__ b3,
    float* __restrict__ out, int nPoints)
{
    const int lane = threadIdx.x & 63;
    const int l15  = lane & 15;
    const int quad = lane >> 4;
    const int wib  = threadIdx.x >> 6;
    const int tile0 = (blockIdx.x * WPB + wib) * NT;
    const int nTiles = (nPoints + 15) >> 4;
    if (tile0 >= nTiles) return;
    const int maxP = nPoints - 1;

    // ---- loop-invariant weight fragments ----
    // A layout: A[m = lane&15][k = quad*8 + j]. Layer1 K=16 padded to 32;
    // b1 folded at k=16 (quad2 j=0), bfrag's k=16 slot = 1.0.
    half8 A1[4];
#pragma unroll
    for (int t = 0; t < 4; ++t) {
        half8 f = {};
        if (quad < 2) {
            const float* row = W1 + (16 * t + l15) * 16 + quad * 8;
#pragma unroll
            for (int j = 0; j < 8; ++j) f[j] = (_Float16)row[j];
        } else if (quad == 2) {
            f[0] = (_Float16)b1[16 * t + l15];
        }
        A1[t] = f;
    }
    half8 A2[4][2];
#pragma unroll
    for (int t = 0; t < 4; ++t)
#pragma unroll
        for (int kk = 0; kk < 2; ++kk) {
            const float* row = W2 + (16 * t + l15) * 64 + 32 * kk + 8 * quad;
            half8 f;
#pragma unroll
            for (int j = 0; j < 8; ++j) f[j] = (_Float16)row[j];
            A2[t][kk] = f;
        }
    // C/D layout: col = lane&15 (point), row = quad*4 + reg.
    float4v bias2[4];
    float w3v[4][4];
#pragma unroll
    for (int t = 0; t < 4; ++t)
#pragma unroll
        for (int r = 0; r < 4; ++r) {
            int h = 16 * t + 4 * quad + r;
            bias2[t][r] = b2[h];
            w3v[t][r]   = W3[h];
        }
    const float bias3 = b3[0];

    // layer1->layer2 cross-quad shuffle plan
    const int src0 = l15 + 16 * ((2 * quad) & 3);
    const int src1 = l15 + 16 * ((2 * quad + 1) & 3);
    const bool sel = (quad >> 1) != 0;

    // ---- register pipeline state ----
    // pts ring: 6 tiles deep (each lane holds point l15's coords; 4-way
    // redundant across quads -> same-line merge in the coalescer).
    float Px[6], Py[6], Pz[6];
    // feature prefetch: 4 tiles deep; lane (quad<2, l15) owns feats
    // quad*8..quad*8+7 of point l15 (= its layer-1 B fragment, pre-cvt).
    float4 Fa[4], Fb[4];

    auto loadPts = [&](int slot, int u) {
        int p = (tile0 + u) * 16 + l15;
        p = p > maxP ? maxP : p;
        const float* q = pts + 3 * p;
        Px[slot] = q[0]; Py[slot] = q[1]; Pz[slot] = q[2];
    };
    auto loadFeat = [&](int fslot, int pslot) {
        if (quad < 2) {
            const int ix = (int)rintf(fminf(fmaxf(Px[pslot] * 127.0f, 0.0f), 127.0f));
            const int iy = (int)rintf(fminf(fmaxf(Py[pslot] * 127.0f, 0.0f), 127.0f));
            const int iz = (int)rintf(fminf(fmaxf(Pz[pslot] * 127.0f, 0.0f), 127.0f));
            const int ofs = ((((ix << 7) | iy) << 7) | iz) << 4;  // floats
            const float4* g = reinterpret_cast<const float4*>(grid + ofs + (quad << 3));
            Fa[fslot] = g[0];
            Fb[fslot] = g[1];
        }
    };

    // ---- prologue: fill rings ----
    loadPts(0, 0); loadPts(1, 1); loadPts(2, 2);
    loadPts(3, 3); loadPts(4, 4); loadPts(5, 5);
    loadFeat(0, 0);   // tile 0
    loadFeat(1, 1);   // tile 1
    loadFeat(2, 2);   // tile 2
    loadFeat(3, 3);   // tile 3

    float o[4];

#pragma unroll
    for (int u = 0; u < NT; ++u) {
        // ---- CONSUME feat slot u&3 first (tile u's features -> bfrag) ----
        // f32->f16 converts copy the values out; only then may the slot be
        // refilled (R8's bug: refill-before-consume).
        half8 bfrag = {};
        if (quad < 2) {
            const float4 f0 = Fa[u & 3];
            const float4 f1 = Fb[u & 3];
            bfrag[0] = (_Float16)f0.x; bfrag[1] = (_Float16)f0.y;
            bfrag[2] = (_Float16)f0.z; bfrag[3] = (_Float16)f0.w;
            bfrag[4] = (_Float16)f1.x; bfrag[5] = (_Float16)f1.y;
            bfrag[6] = (_Float16)f1.z; bfrag[7] = (_Float16)f1.w;
        } else if (quad == 2) {
            bfrag[0] = (_Float16)1.0f;  // multiplies the folded b1 column
        }

        // ---- refill pipeline: these fly across this tile's compute ----
        // feat tile u+4 uses pts slot (u+4)%6 (written at iter u-2);
        // pts slot u%6 (tile u+6) was last read at iter u-4.
        if (u + 4 < NT) loadFeat(u & 3, (u + 4) % 6);
        if (u + 6 < NT) loadPts(u % 6, u + 6);

        // layer 1 (bias via folded K-slot)
        float4v C1[4];
#pragma unroll
        for (int t = 0; t < 4; ++t) {
            float4v zacc = {};
            C1[t] = __builtin_amdgcn_mfma_f32_16x16x32_f16(A1[t], bfrag, zacc, 0, 0, 0);
        }

        // relu + fp16 pack
        uint32_t P[4][2];
#pragma unroll
        for (int t = 0; t < 4; ++t) {
            P[t][0] = pack_f16x2(fmaxf(C1[t][0], 0.0f), fmaxf(C1[t][1], 0.0f));
            P[t][1] = pack_f16x2(fmaxf(C1[t][2], 0.0f), fmaxf(C1[t][3], 0.0f));
        }

        // cross-quad shuffle into layer-2 B fragments
        union Frag { uint32_t u[4]; half8 h; } B2[2];
#pragma unroll
        for (int kk = 0; kk < 2; ++kk) {
            const uint32_t x0a = (uint32_t)__shfl((int)P[2 * kk    ][0], src0);
            const uint32_t x0b = (uint32_t)__shfl((int)P[2 * kk + 1][0], src0);
            const uint32_t x1a = (uint32_t)__shfl((int)P[2 * kk    ][1], src0);
            const uint32_t x1b = (uint32_t)__shfl((int)P[2 * kk + 1][1], src0);
            const uint32_t y0a = (uint32_t)__shfl((int)P[2 * kk    ][0], src1);
            const uint32_t y0b = (uint32_t)__shfl((int)P[2 * kk + 1][0], src1);
            const uint32_t y1a = (uint32_t)__shfl((int)P[2 * kk    ][1], src1);
            const uint32_t y1b = (uint32_t)__shfl((int)P[2 * kk + 1][1], src1);
            B2[kk].u[0] = sel ? x0b : x0a;
            B2[kk].u[1] = sel ? x1b : x1a;
            B2[kk].u[2] = sel ? y0b : y0a;
            B2[kk].u[3] = sel ? y1b : y1a;
        }

        // layer 2 (bias as initial accumulator)
        float4v C2[4];
#pragma unroll
        for (int t = 0; t < 4; ++t) C2[t] = bias2[t];
#pragma unroll
        for (int kk = 0; kk < 2; ++kk)
#pragma unroll
            for (int t = 0; t < 4; ++t)
                C2[t] = __builtin_amdgcn_mfma_f32_16x16x32_f16(A2[t][kk], B2[kk].h, C2[t], 0, 0, 0);

        // layer 3: dot(relu(h2), w3), reduce across quads (broadcasts)
        float z = 0.0f;
#pragma unroll
        for (int t = 0; t < 4; ++t)
#pragma unroll
            for (int r = 0; r < 4; ++r)
                z = fmaf(fmaxf(C2[t][r], 0.0f), w3v[t][r], z);
        z += __shfl_xor(z, 16);
        z += __shfl_xor(z, 32);
        const float e = __expf(2.0f * (z + bias3));
        o[u & 3] = fmaf(-2.0f, __builtin_amdgcn_rcpf(e + 1.0f), 1.0f);

        // every 4 tiles: one coalesced 256B store (64 points)
        if ((u & 3) == 3) {
            const float osel = (quad == 0) ? o[0] : (quad == 1) ? o[1]
                             : (quad == 2) ? o[2] : o[3];
            const int pstore = (tile0 + (u & ~3)) * 16 + lane;
            if (pstore <= maxP) out[pstore] = osel;
        }

        // pin the load schedule to the written pipeline depth: memory ops
        // cannot cross this fence; VALU/MFMA still schedule freely.
        asm volatile("" ::: "memory");
    }
}

extern "C" void kernel_launch(void* const* d_in, const int* in_sizes, int n_in,
                              void* d_out, int out_size, void* d_ws, size_t ws_size,
                              hipStream_t stream)
{
    const float* pts  = (const float*)d_in[0];
    const float* grid = (const float*)d_in[1];
    const float* W1   = (const float*)d_in[2];
    const float* b1   = (const float*)d_in[3];
    const float* W2   = (const float*)d_in[4];
    const float* b2   = (const float*)d_in[5];
    const float* W3   = (const float*)d_in[6];
    const float* b3   = (const float*)d_in[7];
    float* out = (float*)d_out;
    const int nPoints = in_sizes[0] / 3;

    const int nTiles = (nPoints + 15) >> 4;
    const int tilesPerBlock = WPB * NT;              // 64
    const int nBlocks = (nTiles + tilesPerBlock - 1) / tilesPerBlock;  // 2048

    occ_mlp_kernel<<<dim3(nBlocks), dim3(256), 0, stream>>>(
        pts, grid, W1, b1, W2, b2, W3, b3, out, nPoints);
}

// Round 6
// 249.725 us; speedup vs baseline: 1.4453x; 1.0488x over previous
//
#include <hip/hip_runtime.h>
#include <hip/hip_fp16.h>
#include <cstdint>
#include <cstddef>

// OccupancyModel: feats = grid[round(clip(p*127))]  (2M x 16 gather)
//   h1 = relu(feats @ W1^T + b1); h2 = relu(h1 @ W2^T + b2); occ = tanh(h2 @ W3^T + b3)
//
// R12: dual-tile full-lane gather. R11 (105us, no spill) still latency-
// bound: MfmaUtil 9.4 / VALU 35 / HBM 18%, ~50% of issue slots empty;
// depth 2->4 only bought 10%. This round doubles depth again WITHOUT
// register growth by using all 64 lanes per gather: each iteration covers
// a PAIR of tiles - lanes 0-31 (quads 0,1) load tile A's 64B cells, lanes
// 32-63 (quads 2,3) load tile B's. Tile B's fragment comes back to quads
// 0,1 via 8 conflict-free __shfl_xor(.,32). Wins: 8 tiles in flight for
// the same 32 feat VGPRs; feat VMEM instrs halved (1/tile, 1KB each);
// pts loads halved (2x redundancy, was 4x); address-chain VALU halved;
// coords ring 18->9 regs. Consume-before-refill preserved (refill slot
// != consume slot by construction); bounds(256,3) kept (R10 anti-spill).
//
// Pipeline (pair v): consume feat slot v&3 (pair v; issued at v-3, ~3
// pair-computes of cover) -> refill feat slot (v+3)&3 for pair v+3 using
// coords slot v%3 (loaded at v-2) -> load coords pair v+5 into slot
// (v+2)%3. Prologue fills coords 0-2, feats 0-2, then coords 3,4.
//
// MLP core verified R1-R11 (absmax 1.95e-3): fp16 MFMA 16x16x32,
// H^T = W @ feats^T, points on n-dim (col=lane&15); b1 folded into the
// layer-1 K-pad slot; layer1->2 relayout via 16 cross-quad shuffles;
// tanh = 1 - 2/(exp(2x)+1).

typedef _Float16 half8 __attribute__((ext_vector_type(8)));
typedef float float4v __attribute__((ext_vector_type(4)));

#define WPB 4   // waves per block
#define NT  16  // tiles per wave (256 points)
#define NP  8   // tile-pairs per wave

__device__ inline uint32_t pack_f16x2(float a, float b) {
    union { _Float16 h[2]; uint32_t u; } v;
    v.h[0] = (_Float16)a;
    v.h[1] = (_Float16)b;
    return v.u;
}

__global__ __launch_bounds__(256, 3) void occ_mlp_kernel(
    const float* __restrict__ pts,
    const float* __restrict__ grid,
    const float* __restrict__ W1, const float* __restrict__ b1,
    const float* __restrict__ W2, const float* __restrict__ b2,
    const float* __restrict__ W3, const float* __restrict__ b3,
    float* __restrict__ out, int nPoints)
{
    const int lane = threadIdx.x & 63;
    const int l15  = lane & 15;
    const int quad = lane >> 4;
    const int wib  = threadIdx.x >> 6;
    const int tile0 = (blockIdx.x * WPB + wib) * NT;
    const int nTiles = (nPoints + 15) >> 4;
    if (tile0 >= nTiles) return;
    const int maxP = nPoints - 1;
    const int pt0  = tile0 << 4;

    // gather-lane mapping: quads 0,1 own tile A of the pair (halves 0,1 of
    // each point's 64B cell); quads 2,3 own tile B (halves 0,1).
    const int half = quad & 1;   // which 32B half of the cell this lane loads
    const int tsel = quad >> 1;  // 0 = tile A's points, 1 = tile B's points

    // ---- loop-invariant weight fragments ----
    // A layout: A[m = lane&15][k = quad*8 + j]. Layer1 K=16 padded to 32;
    // b1 folded at k=16 (quad2 j=0), bfrag's k=16 slot = 1.0.
    half8 A1[4];
#pragma unroll
    for (int t = 0; t < 4; ++t) {
        half8 f = {};
        if (quad < 2) {
            const float* row = W1 + (16 * t + l15) * 16 + quad * 8;
#pragma unroll
            for (int j = 0; j < 8; ++j) f[j] = (_Float16)row[j];
        } else if (quad == 2) {
            f[0] = (_Float16)b1[16 * t + l15];
        }
        A1[t] = f;
    }
    half8 A2[4][2];
#pragma unroll
    for (int t = 0; t < 4; ++t)
#pragma unroll
        for (int kk = 0; kk < 2; ++kk) {
            const float* row = W2 + (16 * t + l15) * 64 + 32 * kk + 8 * quad;
            half8 f;
#pragma unroll
            for (int j = 0; j < 8; ++j) f[j] = (_Float16)row[j];
            A2[t][kk] = f;
        }
    // C/D layout: col = lane&15 (point), row = quad*4 + reg.
    float4v bias2[4];
    float w3v[4][4];
#pragma unroll
    for (int t = 0; t < 4; ++t)
#pragma unroll
        for (int r = 0; r < 4; ++r) {
            int h = 16 * t + 4 * quad + r;
            bias2[t][r] = b2[h];
            w3v[t][r]   = W3[h];
        }
    const float bias3 = b3[0];

    // layer1->layer2 cross-quad shuffle plan
    const int src0 = l15 + 16 * ((2 * quad) & 3);
    const int src1 = l15 + 16 * ((2 * quad + 1) & 3);
    const bool sel = (quad >> 1) != 0;

    // ---- register pipeline state (pair-granular) ----
    // coords ring: 3 pairs deep; lane holds coords of ITS gather point
    // (2x redundant across the half-pair of quads).
    float Cx[3], Cy[3], Cz[3];
    // feature ring: 4 pairs deep (8 tiles in flight).
    float4 Fa[4], Fb[4];

    auto loadCoords = [&](int slot, int v) {
        int p = pt0 + v * 32 + (tsel << 4) + l15;
        p = p > maxP ? maxP : p;
        const float* q = pts + 3 * p;
        Cx[slot] = q[0]; Cy[slot] = q[1]; Cz[slot] = q[2];
    };
    auto loadFeat = [&](int fslot, int cslot) {
        const int ix = (int)rintf(fminf(fmaxf(Cx[cslot] * 127.0f, 0.0f), 127.0f));
        const int iy = (int)rintf(fminf(fmaxf(Cy[cslot] * 127.0f, 0.0f), 127.0f));
        const int iz = (int)rintf(fminf(fmaxf(Cz[cslot] * 127.0f, 0.0f), 127.0f));
        const int ofs = ((((ix << 7) | iy) << 7) | iz) << 4;  // floats
        const float4* g = reinterpret_cast<const float4*>(grid + ofs + (half << 3));
        Fa[fslot] = g[0];
        Fb[fslot] = g[1];
    };

    // ---- prologue ----
    loadCoords(0, 0); loadCoords(1, 1); loadCoords(2, 2);
    loadFeat(0, 0); loadFeat(1, 1); loadFeat(2, 2);  // pairs 0..2 (one stall here)
    loadCoords(0, 3); loadCoords(1, 4);              // slots 0,1 -> pairs 3,4

    float o[4];

#pragma unroll
    for (int v = 0; v < NP; ++v) {
        const int s = v & 3;

#pragma unroll
        for (int tt = 0; tt < 2; ++tt) {
            const int u = 2 * v + tt;  // tile index within wave

            // ---- B-fragment source for this tile ----
            float4 f0, f1;
            if (tt == 0) {           // tile A: local data (quads 0,1 own it)
                f0 = Fa[s];
                f1 = Fb[s];
            } else {                 // tile B: pull from lanes +32 (quads 2,3)
                f0.x = __shfl_xor(Fa[s].x, 32); f0.y = __shfl_xor(Fa[s].y, 32);
                f0.z = __shfl_xor(Fa[s].z, 32); f0.w = __shfl_xor(Fa[s].w, 32);
                f1.x = __shfl_xor(Fb[s].x, 32); f1.y = __shfl_xor(Fb[s].y, 32);
                f1.z = __shfl_xor(Fb[s].z, 32); f1.w = __shfl_xor(Fb[s].w, 32);
            }

            half8 bfrag = {};
            if (quad < 2) {
                bfrag[0] = (_Float16)f0.x; bfrag[1] = (_Float16)f0.y;
                bfrag[2] = (_Float16)f0.z; bfrag[3] = (_Float16)f0.w;
                bfrag[4] = (_Float16)f1.x; bfrag[5] = (_Float16)f1.y;
                bfrag[6] = (_Float16)f1.z; bfrag[7] = (_Float16)f1.w;
            } else if (quad == 2) {
                bfrag[0] = (_Float16)1.0f;  // multiplies the folded b1 column
            }

            // ---- refill (once per pair, after tile A's consume; targets
            // slots != s, so no aliasing with this pair's data) ----
            if (tt == 0) {
                if (v + 3 < NP) loadFeat((v + 3) & 3, v % 3);
                if (v + 5 < NP) loadCoords((v + 2) % 3, v + 5);
            }

            // layer 1 (bias via folded K-slot)
            float4v C1[4];
#pragma unroll
            for (int t = 0; t < 4; ++t) {
                float4v zacc = {};
                C1[t] = __builtin_amdgcn_mfma_f32_16x16x32_f16(A1[t], bfrag, zacc, 0, 0, 0);
            }

            // relu + fp16 pack
            uint32_t P[4][2];
#pragma unroll
            for (int t = 0; t < 4; ++t) {
                P[t][0] = pack_f16x2(fmaxf(C1[t][0], 0.0f), fmaxf(C1[t][1], 0.0f));
                P[t][1] = pack_f16x2(fmaxf(C1[t][2], 0.0f), fmaxf(C1[t][3], 0.0f));
            }

            // cross-quad shuffle into layer-2 B fragments
            union Frag { uint32_t u[4]; half8 h; } B2[2];
#pragma unroll
            for (int kk = 0; kk < 2; ++kk) {
                const uint32_t x0a = (uint32_t)__shfl((int)P[2 * kk    ][0], src0);
                const uint32_t x0b = (uint32_t)__shfl((int)P[2 * kk + 1][0], src0);
                const uint32_t x1a = (uint32_t)__shfl((int)P[2 * kk    ][1], src0);
                const uint32_t x1b = (uint32_t)__shfl((int)P[2 * kk + 1][1], src0);
                const uint32_t y0a = (uint32_t)__shfl((int)P[2 * kk    ][0], src1);
                const uint32_t y0b = (uint32_t)__shfl((int)P[2 * kk + 1][0], src1);
                const uint32_t y1a = (uint32_t)__shfl((int)P[2 * kk    ][1], src1);
                const uint32_t y1b = (uint32_t)__shfl((int)P[2 * kk + 1][1], src1);
                B2[kk].u[0] = sel ? x0b : x0a;
                B2[kk].u[1] = sel ? x1b : x1a;
                B2[kk].u[2] = sel ? y0b : y0a;
                B2[kk].u[3] = sel ? y1b : y1a;
            }

            // layer 2 (bias as initial accumulator)
            float4v C2[4];
#pragma unroll
            for (int t = 0; t < 4; ++t) C2[t] = bias2[t];
#pragma unroll
            for (int kk = 0; kk < 2; ++kk)
#pragma unroll
                for (int t = 0; t < 4; ++t)
                    C2[t] = __builtin_amdgcn_mfma_f32_16x16x32_f16(A2[t][kk], B2[kk].h, C2[t], 0, 0, 0);

            // layer 3: dot(relu(h2), w3), reduce across quads (broadcasts)
            float z = 0.0f;
#pragma unroll
            for (int t = 0; t < 4; ++t)
#pragma unroll
                for (int r = 0; r < 4; ++r)
                    z = fmaf(fmaxf(C2[t][r], 0.0f), w3v[t][r], z);
            z += __shfl_xor(z, 16);
            z += __shfl_xor(z, 32);
            const float e = __expf(2.0f * (z + bias3));
            o[u & 3] = fmaf(-2.0f, __builtin_amdgcn_rcpf(e + 1.0f), 1.0f);

            // every 4 tiles: one coalesced 256B store (64 points)
            if ((u & 3) == 3) {
                const float osel = (quad == 0) ? o[0] : (quad == 1) ? o[1]
                                 : (quad == 2) ? o[2] : o[3];
                const int pstore = (tile0 + (u & ~3)) * 16 + lane;
                if (pstore <= maxP) out[pstore] = osel;
            }
        }

        // pin the load schedule to the written pipeline depth: memory ops
        // cannot cross this fence; VALU/MFMA still schedule freely.
        asm volatile("" ::: "memory");
    }
}

extern "C" void kernel_launch(void* const* d_in, const int* in_sizes, int n_in,
                              void* d_out, int out_size, void* d_ws, size_t ws_size,
                              hipStream_t stream)
{
    const float* pts  = (const float*)d_in[0];
    const float* grid = (const float*)d_in[1];
    const float* W1   = (const float*)d_in[2];
    const float* b1   = (const float*)d_in[3];
    const float* W2   = (const float*)d_in[4];
    const float* b2   = (const float*)d_in[5];
    const float* W3   = (const float*)d_in[6];
    const float* b3   = (const float*)d_in[7];
    float* out = (float*)d_out;
    const int nPoints = in_sizes[0] / 3;

    const int nTiles = (nPoints + 15) >> 4;
    const int tilesPerBlock = WPB * NT;              // 64
    const int nBlocks = (nTiles + tilesPerBlock - 1) / tilesPerBlock;  // 2048

    occ_mlp_kernel<<<dim3(nBlocks), dim3(256), 0, stream>>>(
        pts, grid, W1, b1, W2, b2, W3, b3, out, nPoints);
}